// Round 7
// baseline (67.596 us; speedup 1.0000x reference)
//
#include <hip/hip_runtime.h>

// SoftClusterGaussianHead — fused two-phase kernel, occupancy+ILP round.
// B=8, N=4096, D=512, K=8.
// sigma = S2 + (S0-2)*S1^2 with S0=sum_n p, S1=sum_n p*x, S2=sum_n p*x^2.
// Phase 1: softmax p -> LDS (2-row ILP pairs, all x preloaded).
// Phase 2: moment accumulation (x re-read L2-hot), LDS merge, coalesced flush.
// ws: partial[b][chunk][k][d][2] | s0g[b][k]

typedef float v2f __attribute__((ext_vector_type(2)));

#define B_ 8
#define N_ 4096
#define D_ 512
#define K_ 8
#define EPS_ 1e-6f
#define CHUNKS 128           // blocks per b
#define ROWS_PB 32           // rows per block
#define PART_FLOATS(cs) ((size_t)B_ * (cs) * K_ * D_ * 2)

__global__ __launch_bounds__(512, 2)
void k1_fused(const float* __restrict__ x, const float* __restrict__ W,
              const float* __restrict__ bias, float* __restrict__ partial,
              float* __restrict__ s0g, int cstride, int atomic_mode) {
#pragma clang fp contract(fast)
  const int lane = threadIdx.x & 63;
  const int wave = threadIdx.x >> 6;
  const int b     = blockIdx.x >> 7;
  const int chunk = blockIdx.x & 127;

  __shared__ float p_lds[ROWS_PB][K_];   // 1 KB
  __shared__ v2f   comb[4][16][64];      // 32 KB
  __shared__ float s0sh[8][K_];          // 256 B

  const float* xb = x + ((size_t)b * N_ + (size_t)chunk * ROWS_PB) * D_;

  // ---------------- phase 1: softmax probs (lane owns d = 8*lane..8*lane+7) ----
  {
    v2f wk[8][4];
#pragma unroll
    for (int dj = 0; dj < 8; ++dj) {
      const float4* wr = reinterpret_cast<const float4*>(&W[(8 * lane + dj) * K_]);
      float4 wa = wr[0], wb4 = wr[1];
      wk[dj][0] = (v2f){wa.x, wa.y};  wk[dj][1] = (v2f){wa.z, wa.w};
      wk[dj][2] = (v2f){wb4.x, wb4.y}; wk[dj][3] = (v2f){wb4.z, wb4.w};
    }
    const float biasv = bias[lane & 7];
    const bool c0 = (lane & 1) != 0;
    const bool c1 = (lane & 2) != 0;
    const bool c2 = (lane & 4) != 0;

    auto row_softmax = [&](float4 xa, float4 xc) -> float {
      float xv[8] = {xa.x, xa.y, xa.z, xa.w, xc.x, xc.y, xc.z, xc.w};
      v2f qp[4] = {(v2f){0,0},(v2f){0,0},(v2f){0,0},(v2f){0,0}};
#pragma unroll
      for (int dj = 0; dj < 8; ++dj) {
        v2f xx = (v2f){xv[dj], xv[dj]};
#pragma unroll
        for (int kp = 0; kp < 4; ++kp) qp[kp] += wk[dj][kp] * xx;
      }
      float q0=qp[0].x,q1=qp[0].y,q2=qp[1].x,q3=qp[1].y;
      float q4=qp[2].x,q5=qp[2].y,q6=qp[3].x,q7=qp[3].y;
      // reduce-scatter butterfly: lane ends with full logit for k = lane&7
      float r0 = c0 ? q0 : q1, r1 = c0 ? q2 : q3, r2 = c0 ? q4 : q5, r3 = c0 ? q6 : q7;
      r0 = __shfl_xor(r0, 1, 64); r1 = __shfl_xor(r1, 1, 64);
      r2 = __shfl_xor(r2, 1, 64); r3 = __shfl_xor(r3, 1, 64);
      float a0 = (c0 ? q1 : q0) + r0, a1 = (c0 ? q3 : q2) + r1;
      float a2 = (c0 ? q5 : q4) + r2, a3 = (c0 ? q7 : q6) + r3;
      float sg0 = c1 ? a0 : a1, sg1 = c1 ? a2 : a3;
      sg0 = __shfl_xor(sg0, 2, 64); sg1 = __shfl_xor(sg1, 2, 64);
      float b0 = (c1 ? a1 : a0) + sg0, b1 = (c1 ? a3 : a2) + sg1;
      float g0 = c2 ? b0 : b1;
      g0 = __shfl_xor(g0, 4, 64);
      float t = (c2 ? b1 : b0) + g0;
      t += __shfl_xor(t, 8, 64);
      t += __shfl_xor(t, 16, 64);
      t += __shfl_xor(t, 32, 64);
      t += biasv;
      // softmax in transposed (one-k-per-lane) form
      float mx = fmaxf(t, __shfl_xor(t, 1, 64));
      mx = fmaxf(mx, __shfl_xor(mx, 2, 64));
      mx = fmaxf(mx, __shfl_xor(mx, 4, 64));
      float e = __expf(t - mx);
      float se = e + __shfl_xor(e, 1, 64);
      se += __shfl_xor(se, 2, 64);
      se += __shfl_xor(se, 4, 64);
      return e * __builtin_amdgcn_rcpf(se);
    };

    // preload the wave's 4 rows entirely (32 VGPRs), then 2x 2-row ILP passes
    const int r0 = wave * 4;
    const float4* x0 = reinterpret_cast<const float4*>(&xb[(size_t)(r0 + 0) * D_]);
    const float4* x1 = reinterpret_cast<const float4*>(&xb[(size_t)(r0 + 1) * D_]);
    const float4* x2 = reinterpret_cast<const float4*>(&xb[(size_t)(r0 + 2) * D_]);
    const float4* x3 = reinterpret_cast<const float4*>(&xb[(size_t)(r0 + 3) * D_]);
    float4 a0 = x0[2 * lane], c0v = x0[2 * lane + 1];
    float4 a1 = x1[2 * lane], c1v = x1[2 * lane + 1];
    float4 a2 = x2[2 * lane], c2v = x2[2 * lane + 1];
    float4 a3 = x3[2 * lane], c3v = x3[2 * lane + 1];

    float pm0 = row_softmax(a0, c0v);
    float pm1 = row_softmax(a1, c1v);
    float pm2 = row_softmax(a2, c2v);
    float pm3 = row_softmax(a3, c3v);

    if (lane < K_) {
      p_lds[r0 + 0][lane] = pm0;
      p_lds[r0 + 1][lane] = pm1;
      p_lds[r0 + 2][lane] = pm2;
      p_lds[r0 + 3][lane] = pm3;
      s0sh[wave][lane] = pm0 + pm1 + pm2 + pm3;
    }
  }
  __syncthreads();

  if (threadIdx.x < K_) {
    float s = 0.f;
#pragma unroll
    for (int w = 0; w < 8; ++w) s += s0sh[w][threadIdx.x];
    atomicAdd(s0g + b * K_ + threadIdx.x, s);
  }

  // ---------------- phase 2: moments. wave = (k-pair q, row-half h) -----------
  const int q = wave & 3;
  const int h = wave >> 2;
  const int rbase = h * 16;

  v2f acc[8][2];
#pragma unroll
  for (int dj = 0; dj < 8; ++dj) { acc[dj][0] = (v2f){0,0}; acc[dj][1] = (v2f){0,0}; }

  // software-pipelined: prefetch next row's x and p
  const float4* xr0 = reinterpret_cast<const float4*>(&xb[(size_t)rbase * D_]);
  float4 xa = xr0[2 * lane];
  float4 xc = xr0[2 * lane + 1];
  v2f pk = *reinterpret_cast<const v2f*>(&p_lds[rbase][2 * q]);

  for (int r = 0; r < 16; ++r) {
    const int nr = rbase + ((r + 1 < 16) ? r + 1 : r);
    const float4* xrn = reinterpret_cast<const float4*>(&xb[(size_t)nr * D_]);
    float4 na = xrn[2 * lane];
    float4 nc = xrn[2 * lane + 1];
    v2f npk = *reinterpret_cast<const v2f*>(&p_lds[nr][2 * q]);

    float xv[8] = {xa.x, xa.y, xa.z, xa.w, xc.x, xc.y, xc.z, xc.w};
    v2f p0 = (v2f){pk.x, pk.x};
    v2f p1 = (v2f){pk.y, pk.y};
#pragma unroll
    for (int dj = 0; dj < 8; ++dj) {
      v2f m2 = (v2f){xv[dj], xv[dj] * xv[dj]};
      acc[dj][0] += m2 * p0;
      acc[dj][1] += m2 * p1;
    }
    xa = na; xc = nc; pk = npk;
  }

  // row-half merge via LDS, then coalesced flush by h==0 waves
  if (h == 1) {
#pragma unroll
    for (int dj = 0; dj < 8; ++dj) {
      comb[q][dj * 2 + 0][lane] = acc[dj][0];
      comb[q][dj * 2 + 1][lane] = acc[dj][1];
    }
  }
  __syncthreads();

  if (h == 0) {
    const int cslot = atomic_mode ? 0 : chunk;
#pragma unroll
    for (int kk = 0; kk < 2; ++kk) {
      const int k = 2 * q + kk;
      float* dst = partial + (((size_t)(b * cstride + cslot) * K_ + k) * D_ + 8 * lane) * 2;
#pragma unroll
      for (int g = 0; g < 4; ++g) {
        v2f u0 = acc[2 * g][kk]     + comb[q][(2 * g) * 2 + kk][lane];
        v2f u1 = acc[2 * g + 1][kk] + comb[q][(2 * g + 1) * 2 + kk][lane];
        if (atomic_mode) {
          atomicAdd(dst + g * 4 + 0, u0.x); atomicAdd(dst + g * 4 + 1, u0.y);
          atomicAdd(dst + g * 4 + 2, u1.x); atomicAdd(dst + g * 4 + 3, u1.y);
        } else {
          float4 v; v.x = u0.x; v.y = u0.y; v.z = u1.x; v.w = u1.y;
          *reinterpret_cast<float4*>(dst + g * 4) = v;   // 64B-aligned, coalesced
        }
      }
    }
  }
}

// ---------------- k2: finalize ----------------
// grid = B*32 slices, 256 thr: cq(2) x k(8) x dl(16); cq splits the chunk sum.
__global__ __launch_bounds__(256)
void k2_final(const float* __restrict__ partial, const float* __restrict__ s0g,
              const float* __restrict__ eps, float* __restrict__ out,
              int cstride, int nchunks) {
  const int b = blockIdx.x >> 5;
  const int slice = blockIdx.x & 31;
  const int tid = threadIdx.x;
  const int cq = tid >> 7;
  const int k  = (tid >> 4) & 7;
  const int dl = tid & 15;
  const int d  = slice * 16 + dl;

  __shared__ v2f red2[2][K_][16];
  __shared__ float zsh[K_][16];
  __shared__ float klsh[4];

  const int half = (nchunks + 1) >> 1;
  const int cbeg = cq * half;
  const int cend = (cbeg + half < nchunks) ? (cbeg + half) : nchunks;

  const float* base = partial + (((size_t)b * cstride) * K_ + k) * D_ * 2 + d * 2;
  const size_t cstep = (size_t)K_ * D_ * 2;

  v2f s0v = (v2f){0,0}, s1v = (v2f){0,0}, s2v = (v2f){0,0}, s3v = (v2f){0,0};
  int c = cbeg;
  for (; c + 4 <= cend; c += 4) {
    s0v += *reinterpret_cast<const v2f*>(base + (size_t)c * cstep);
    s1v += *reinterpret_cast<const v2f*>(base + (size_t)(c + 1) * cstep);
    s2v += *reinterpret_cast<const v2f*>(base + (size_t)(c + 2) * cstep);
    s3v += *reinterpret_cast<const v2f*>(base + (size_t)(c + 3) * cstep);
  }
  for (; c < cend; ++c) s0v += *reinterpret_cast<const v2f*>(base + (size_t)c * cstep);
  red2[cq][k][dl] = (s0v + s1v) + (s2v + s3v);
  __syncthreads();

  float klp = 0.f;
  if (cq == 0) {
    v2f sv = red2[0][k][dl] + red2[1][k][dl];
    const float S1 = sv.x, S2 = sv.y;
    const float S0 = s0g[b * K_ + k];
    float sigraw = S2 + (S0 - 2.f) * S1 * S1;
    float sig = fmaxf(sigraw, 0.f) + EPS_;
    float z = S1 + eps[((size_t)(b * K_ + k)) * D_ + d] * sqrtf(sig);
    zsh[k][dl] = z;
    klp = 1.f + logf(sig) - S1 * S1 - sigraw;
  }

  klp += __shfl_xor(klp, 1, 64);
  klp += __shfl_xor(klp, 2, 64);
  klp += __shfl_xor(klp, 4, 64);
  klp += __shfl_xor(klp, 8, 64);
  klp += __shfl_xor(klp, 16, 64);
  klp += __shfl_xor(klp, 32, 64);
  const int lane = tid & 63, wv = tid >> 6;
  if (lane == 0) klsh[wv] = klp;
  __syncthreads();

  if (tid < 16) {
    float pooled = 0.f;
#pragma unroll
    for (int kk = 0; kk < K_; ++kk) pooled += zsh[kk][tid];
    out[b * D_ + slice * 16 + tid] = pooled * 0.125f;
  }
  if (tid == 0) {
    atomicAdd(out + B_ * D_, (klsh[0] + klsh[1] + klsh[2] + klsh[3]) * (-0.5f / (B_ * K_)));
  }
}

extern "C" void kernel_launch(void* const* d_in, const int* in_sizes, int n_in,
                              void* d_out, int out_size, void* d_ws, size_t ws_size,
                              hipStream_t stream) {
  const float* x    = (const float*)d_in[0];
  const float* W    = (const float*)d_in[1];
  const float* bias = (const float*)d_in[2];
  const float* eps  = (const float*)d_in[3];
  float* out = (float*)d_out;
  float* ws  = (float*)d_ws;

  const size_t full_floats = PART_FLOATS(CHUNKS) + B_ * K_;
  const int atomic_mode = (ws_size < full_floats * sizeof(float)) ? 1 : 0;
  const int cstride = atomic_mode ? 1 : CHUNKS;
  const int nchunks = atomic_mode ? 1 : CHUNKS;

  float* partial = ws;
  float* s0g     = partial + PART_FLOATS(cstride);

  if (atomic_mode) {
    hipMemsetAsync(partial, 0, (PART_FLOATS(1) + B_ * K_) * sizeof(float), stream);
  } else {
    hipMemsetAsync(s0g, 0, B_ * K_ * sizeof(float), stream);
  }
  hipMemsetAsync(out + B_ * D_, 0, sizeof(float), stream);

  k1_fused<<<B_ * CHUNKS, 512, 0, stream>>>(x, W, bias, partial, s0g, cstride, atomic_mode);
  k2_final<<<B_ * 32, 256, 0, stream>>>(partial, s0g, eps, out, cstride, nchunks);
}

// Round 8
// 62.263 us; speedup vs baseline: 1.0856x; 1.0856x over previous
//
#include <hip/hip_runtime.h>

// SoftClusterGaussianHead — fused two-phase kernel, minimal-LDS round.
// B=8, N=4096, D=512, K=8.
// sigma = S2 + (S0-2)*S1^2 with S0=sum_n p, S1=sum_n p*x, S2=sum_n p*x^2.
// Phase 1: logits via reduce-scatter to k-PAIRS (lane&3 -> {k,k+4}), lane-local
//          softmax, p -> LDS (1 KB). Phase 2: wave owns k-pair over all rows,
//          acc in regs, direct coalesced flush (no merge LDS).
// ws: partial[b][chunk][k][d][2] | s0g[b][k]

typedef float v2f __attribute__((ext_vector_type(2)));

#define B_ 8
#define N_ 4096
#define D_ 512
#define K_ 8
#define EPS_ 1e-6f
#define CHUNKS 128           // blocks per b
#define ROWS_PB 32           // rows per block
#define PART_FLOATS(cs) ((size_t)B_ * (cs) * K_ * D_ * 2)

__global__ __launch_bounds__(256, 2)
void k1_fused(const float* __restrict__ x, const float* __restrict__ W,
              const float* __restrict__ bias, float* __restrict__ partial,
              float* __restrict__ s0g, int cstride, int atomic_mode) {
#pragma clang fp contract(fast)
  const int lane = threadIdx.x & 63;
  const int wave = threadIdx.x >> 6;    // 0..3
  const int b     = blockIdx.x >> 7;
  const int chunk = blockIdx.x & 127;

  // p_lds[row][slot]: slot = 2*(k&3) + (k>>2)  (pair-major storage)
  __shared__ float p_lds[ROWS_PB][K_];   // 1 KB
  __shared__ v2f   s0sh[4][4];           // [wave][kq] = (S0_k, S0_k+4)

  const float* xb = x + ((size_t)b * N_ + (size_t)chunk * ROWS_PB) * D_;

  // ---------------- phase 1: softmax probs ----------------
  {
    // lane owns d = 8*lane .. 8*lane+7 ; wk[dj][kp] = (W[d][2kp], W[d][2kp+1])
    v2f wk[8][4];
#pragma unroll
    for (int dj = 0; dj < 8; ++dj) {
      const float4* wr = reinterpret_cast<const float4*>(&W[(8 * lane + dj) * K_]);
      float4 wa = wr[0], wb4 = wr[1];
      wk[dj][0] = (v2f){wa.x, wa.y};   wk[dj][1] = (v2f){wa.z, wa.w};
      wk[dj][2] = (v2f){wb4.x, wb4.y}; wk[dj][3] = (v2f){wb4.z, wb4.w};
    }
    const int kq = lane & 3;
    const v2f biasv2 = (v2f){bias[kq], bias[kq + 4]};
    const bool c0 = (lane & 1) != 0;
    const bool c1 = (lane & 2) != 0;

    // per-row: partial logits -> reduce-scatter to k-pair -> lane-local softmax
    auto row_probs = [&](float4 xa, float4 xc) -> v2f {
      float xv[8] = {xa.x, xa.y, xa.z, xa.w, xc.x, xc.y, xc.z, xc.w};
      v2f qp[4] = {(v2f){0,0},(v2f){0,0},(v2f){0,0},(v2f){0,0}};
#pragma unroll
      for (int dj = 0; dj < 8; ++dj) {
        v2f xx = (v2f){xv[dj], xv[dj]};
#pragma unroll
        for (int kp = 0; kp < 4; ++kp) qp[kp] += wk[dj][kp] * xx;
      }
      float q0=qp[0].x,q1=qp[0].y,q2=qp[1].x,q3=qp[1].y;
      float q4=qp[2].x,q5=qp[2].y,q6=qp[3].x,q7=qp[3].y;

      // stage A (xor 1): even-k lanes keep {0,2,4,6}, odd keep {1,3,5,7}
      float r0 = c0 ? q0 : q1, r1 = c0 ? q2 : q3, r2 = c0 ? q4 : q5, r3 = c0 ? q6 : q7;
      r0 = __shfl_xor(r0, 1, 64); r1 = __shfl_xor(r1, 1, 64);
      r2 = __shfl_xor(r2, 1, 64); r3 = __shfl_xor(r3, 1, 64);
      float a0 = (c0 ? q1 : q0) + r0, a1 = (c0 ? q3 : q2) + r1;
      float a2 = (c0 ? q5 : q4) + r2, a3 = (c0 ? q7 : q6) + r3;
      // stage B (xor 2): lane ends with b = (k=kq, k=kq+4) partial
      float s0_ = c1 ? a0 : a1, s1_ = c1 ? a2 : a3;
      s0_ = __shfl_xor(s0_, 2, 64); s1_ = __shfl_xor(s1_, 2, 64);
      v2f t2 = (v2f){(c1 ? a1 : a0) + s0_, (c1 ? a3 : a2) + s1_};
      // stage C: full butterfly over remaining lane dims (4,8,16,32)
#pragma unroll
      for (int m = 4; m <= 32; m <<= 1) {
        v2f o = (v2f){__shfl_xor(t2.x, m, 64), __shfl_xor(t2.y, m, 64)};
        t2 += o;
      }
      t2 += biasv2;
      // lane-local softmax over 8 k's (4-lane group exchange)
      float mx = fmaxf(t2.x, t2.y);
      mx = fmaxf(mx, __shfl_xor(mx, 1, 64));
      mx = fmaxf(mx, __shfl_xor(mx, 2, 64));
      float ex = __expf(t2.x - mx), ey = __expf(t2.y - mx);
      float se = ex + ey;
      se += __shfl_xor(se, 1, 64);
      se += __shfl_xor(se, 2, 64);
      float inv = __builtin_amdgcn_rcpf(se);
      return (v2f){ex * inv, ey * inv};
    };

    v2f s0acc = (v2f){0.f, 0.f};
    const int r0w = wave * 8;
#pragma unroll
    for (int jp = 0; jp < 4; ++jp) {
      const int j0 = r0w + 2 * jp;
      const float4* x0 = reinterpret_cast<const float4*>(&xb[(size_t)j0 * D_]);
      const float4* x1 = reinterpret_cast<const float4*>(&xb[(size_t)(j0 + 1) * D_]);
      float4 xa0 = x0[2 * lane], xc0 = x0[2 * lane + 1];
      float4 xa1 = x1[2 * lane], xc1 = x1[2 * lane + 1];
      v2f p0 = row_probs(xa0, xc0);
      v2f p1 = row_probs(xa1, xc1);
      s0acc += p0 + p1;
      if (lane < 4) {
        *reinterpret_cast<v2f*>(&p_lds[j0][2 * lane])     = p0;
        *reinterpret_cast<v2f*>(&p_lds[j0 + 1][2 * lane]) = p1;
      }
    }
    if (lane < 4) s0sh[wave][lane] = s0acc;
  }
  __syncthreads();

  if (threadIdx.x < 4) {
    v2f s = s0sh[0][threadIdx.x] + s0sh[1][threadIdx.x] +
            s0sh[2][threadIdx.x] + s0sh[3][threadIdx.x];
    atomicAdd(s0g + b * K_ + threadIdx.x,     s.x);
    atomicAdd(s0g + b * K_ + threadIdx.x + 4, s.y);
  }

  // ---------------- phase 2: moments. wave owns k = {wave, wave+4} ----------
  const int q = wave;

  v2f acc0[8], acc1[8];
#pragma unroll
  for (int dj = 0; dj < 8; ++dj) { acc0[dj] = (v2f){0,0}; acc1[dj] = (v2f){0,0}; }

  // rolling prefetch of next row's x and p
  const float4* xr0 = reinterpret_cast<const float4*>(&xb[0]);
  float4 xa = xr0[2 * lane];
  float4 xc = xr0[2 * lane + 1];
  v2f pk = *reinterpret_cast<const v2f*>(&p_lds[0][2 * q]);

  for (int r = 0; r < ROWS_PB; ++r) {
    const int nr = (r + 1 < ROWS_PB) ? r + 1 : r;
    const float4* xrn = reinterpret_cast<const float4*>(&xb[(size_t)nr * D_]);
    float4 na = xrn[2 * lane];
    float4 nc = xrn[2 * lane + 1];
    v2f npk = *reinterpret_cast<const v2f*>(&p_lds[nr][2 * q]);

    float xv[8] = {xa.x, xa.y, xa.z, xa.w, xc.x, xc.y, xc.z, xc.w};
    v2f ps0 = (v2f){pk.x, pk.x};
    v2f ps1 = (v2f){pk.y, pk.y};
#pragma unroll
    for (int dj = 0; dj < 8; ++dj) {
      v2f m2 = (v2f){xv[dj], xv[dj] * xv[dj]};
      acc0[dj] += m2 * ps0;
      acc1[dj] += m2 * ps1;
    }
    xa = na; xc = nc; pk = npk;
  }

  // direct coalesced flush: k = q (acc0) and q+4 (acc1)
  const int cslot = atomic_mode ? 0 : chunk;
#pragma unroll
  for (int kk = 0; kk < 2; ++kk) {
    const int k = q + 4 * kk;
    v2f* acc = kk ? acc1 : acc0;
    float* dst = partial + (((size_t)(b * cstride + cslot) * K_ + k) * D_ + 8 * lane) * 2;
#pragma unroll
    for (int g = 0; g < 4; ++g) {
      v2f u0 = acc[2 * g];
      v2f u1 = acc[2 * g + 1];
      if (atomic_mode) {
        atomicAdd(dst + g * 4 + 0, u0.x); atomicAdd(dst + g * 4 + 1, u0.y);
        atomicAdd(dst + g * 4 + 2, u1.x); atomicAdd(dst + g * 4 + 3, u1.y);
      } else {
        float4 v; v.x = u0.x; v.y = u0.y; v.z = u1.x; v.w = u1.y;
        *reinterpret_cast<float4*>(dst + g * 4) = v;   // 16B aligned
      }
    }
  }
}

// ---------------- k2: finalize ----------------
// grid = B*32 slices, 256 thr: cq(2) x k(8) x dl(16); cq splits the chunk sum.
__global__ __launch_bounds__(256)
void k2_final(const float* __restrict__ partial, const float* __restrict__ s0g,
              const float* __restrict__ eps, float* __restrict__ out,
              int cstride, int nchunks) {
  const int b = blockIdx.x >> 5;
  const int slice = blockIdx.x & 31;
  const int tid = threadIdx.x;
  const int cq = tid >> 7;
  const int k  = (tid >> 4) & 7;
  const int dl = tid & 15;
  const int d  = slice * 16 + dl;

  __shared__ v2f red2[2][K_][16];
  __shared__ float zsh[K_][16];
  __shared__ float klsh[4];

  const int half = (nchunks + 1) >> 1;
  const int cbeg = cq * half;
  const int cend = (cbeg + half < nchunks) ? (cbeg + half) : nchunks;

  const float* base = partial + (((size_t)b * cstride) * K_ + k) * D_ * 2 + d * 2;
  const size_t cstep = (size_t)K_ * D_ * 2;

  v2f s0v = (v2f){0,0}, s1v = (v2f){0,0}, s2v = (v2f){0,0}, s3v = (v2f){0,0};
  int c = cbeg;
  for (; c + 4 <= cend; c += 4) {
    s0v += *reinterpret_cast<const v2f*>(base + (size_t)c * cstep);
    s1v += *reinterpret_cast<const v2f*>(base + (size_t)(c + 1) * cstep);
    s2v += *reinterpret_cast<const v2f*>(base + (size_t)(c + 2) * cstep);
    s3v += *reinterpret_cast<const v2f*>(base + (size_t)(c + 3) * cstep);
  }
  for (; c < cend; ++c) s0v += *reinterpret_cast<const v2f*>(base + (size_t)c * cstep);
  red2[cq][k][dl] = (s0v + s1v) + (s2v + s3v);
  __syncthreads();

  float klp = 0.f;
  if (cq == 0) {
    v2f sv = red2[0][k][dl] + red2[1][k][dl];
    const float S1 = sv.x, S2 = sv.y;
    const float S0 = s0g[b * K_ + k];
    float sigraw = S2 + (S0 - 2.f) * S1 * S1;
    float sig = fmaxf(sigraw, 0.f) + EPS_;
    float z = S1 + eps[((size_t)(b * K_ + k)) * D_ + d] * sqrtf(sig);
    zsh[k][dl] = z;
    klp = 1.f + logf(sig) - S1 * S1 - sigraw;
  }

  klp += __shfl_xor(klp, 1, 64);
  klp += __shfl_xor(klp, 2, 64);
  klp += __shfl_xor(klp, 4, 64);
  klp += __shfl_xor(klp, 8, 64);
  klp += __shfl_xor(klp, 16, 64);
  klp += __shfl_xor(klp, 32, 64);
  const int lane = tid & 63, wv = tid >> 6;
  if (lane == 0) klsh[wv] = klp;
  __syncthreads();

  if (tid < 16) {
    float pooled = 0.f;
#pragma unroll
    for (int kk = 0; kk < K_; ++kk) pooled += zsh[kk][tid];
    out[b * D_ + slice * 16 + tid] = pooled * 0.125f;
  }
  if (tid == 0) {
    atomicAdd(out + B_ * D_, (klsh[0] + klsh[1] + klsh[2] + klsh[3]) * (-0.5f / (B_ * K_)));
  }
}

extern "C" void kernel_launch(void* const* d_in, const int* in_sizes, int n_in,
                              void* d_out, int out_size, void* d_ws, size_t ws_size,
                              hipStream_t stream) {
  const float* x    = (const float*)d_in[0];
  const float* W    = (const float*)d_in[1];
  const float* bias = (const float*)d_in[2];
  const float* eps  = (const float*)d_in[3];
  float* out = (float*)d_out;
  float* ws  = (float*)d_ws;

  const size_t full_floats = PART_FLOATS(CHUNKS) + B_ * K_;
  const int atomic_mode = (ws_size < full_floats * sizeof(float)) ? 1 : 0;
  const int cstride = atomic_mode ? 1 : CHUNKS;
  const int nchunks = atomic_mode ? 1 : CHUNKS;

  float* partial = ws;
  float* s0g     = partial + PART_FLOATS(cstride);

  if (atomic_mode) {
    hipMemsetAsync(partial, 0, (PART_FLOATS(1) + B_ * K_) * sizeof(float), stream);
  } else {
    hipMemsetAsync(s0g, 0, B_ * K_ * sizeof(float), stream);
  }
  hipMemsetAsync(out + B_ * D_, 0, sizeof(float), stream);

  k1_fused<<<B_ * CHUNKS, 256, 0, stream>>>(x, W, bias, partial, s0g, cstride, atomic_mode);
  k2_final<<<B_ * 32, 256, 0, stream>>>(partial, s0g, eps, out, cstride, nchunks);
}